// Round 13
// baseline (114.293 us; speedup 1.0000x reference)
//
#include <hip/hip_runtime.h>

// SKA: per-pixel dynamic grouped 3x3 conv.
// x: [B=16, C=128, H=56, W=56] f32
// w: [B=16, Cw=16, 9, H=56, W=56] f32   (channel c uses weight channel c % 16)
// out[b,c,h,w] = sum_{i,j} xpad[b,c,h+i,w+j] * w[b, c%16, i*3+j, h, w], pad=1.
//
// Round 13 (= round 12 resubmit — broker timeout): MAX-OCCUPANCY flat kernel.
// One thread per output quad (b,c,h,q): 1,605,632 threads = 6272 blocks =
// ~24.5 waves/CU (2x every prior round).
// Rationale: R2/R8/R11 all converge to 30-33us at 8-12 waves/CU with
// per-iteration latency chains; occupancy is the only untested axis.
// - No LDS / barriers / shuffles; 3 independent guarded row-batches/thread.
// - Row-by-row tap processing keeps VGPR low (3 wk float4 live, not 9).
// - All streams (x, w, out) contiguous 1KB per wave-instruction.
// - 8 channels re-reading the same w rows: same-address lanes coalesce,
//   cross-block reuse served by L2/L3 (w fits Infinity Cache).

#define SKA_B   16
#define SKA_C   128
#define SKA_CW  16
#define SKA_H   56
#define SKA_W   56
#define SKA_HW  (SKA_H * SKA_W)        // 3136
#define SKA_Q   14                     // float4 quads per row

typedef float f32x4 __attribute__((ext_vector_type(4)));

__global__ __launch_bounds__(256, 6) void ska_kernel(
    const float* __restrict__ x,
    const float* __restrict__ w,
    float* __restrict__ out)
{
    const int tid = blockIdx.x * 256 + threadIdx.x;
    // tid -> (b, cw, ch, h, q), q innermost then h: all lane streams contiguous.
    const int q  = tid % SKA_Q;
    int t        = tid / SKA_Q;
    const int h  = t % SKA_H;
    t            = t / SKA_H;
    const int ch = t & 7;              // group 0..7
    t            = t >> 3;
    const int cw = t & 15;
    const int b  = t >> 4;
    // grid exact: 16*16*8*56*14 = 1,605,632 = 6272 * 256

    const int col = q * 4;
    const int hw  = h * SKA_W + col;

    const float* xc = x   + ((size_t)b * SKA_C + ch * SKA_CW + cw) * SKA_HW + hw;
    const float* wp = w   + ((size_t)(b * SKA_CW + cw) * 9) * SKA_HW + hw;
    float*       oc = out + ((size_t)b * SKA_C + ch * SKA_CW + cw) * SKA_HW + hw;

    const bool hv0 = (h > 0);
    const bool hv2 = (h < SKA_H - 1);
    const bool lv  = (q > 0);
    const bool rv  = (q < SKA_Q - 1);

    float a0 = 0.f, a1 = 0.f, a2 = 0.f, a3 = 0.f;

#pragma unroll
    for (int r = 0; r < 3; ++r) {
        if (r == 0 && !hv0) continue;
        if (r == 2 && !hv2) continue;
        const float* xr = xc + (r - 1) * SKA_W;
        const float4 m = *(const float4*)xr;     // aligned center quad
        float L = 0.f, R = 0.f;
        if (lv) L = xr[-1];
        if (rv) R = xr[4];
        // 3 per-pixel weight vectors for this tap row (k = r*3 + j).
        const float4 w0 = *(const float4*)(wp + (size_t)(3 * r + 0) * SKA_HW);
        const float4 w1 = *(const float4*)(wp + (size_t)(3 * r + 1) * SKA_HW);
        const float4 w2 = *(const float4*)(wp + (size_t)(3 * r + 2) * SKA_HW);

        a0 += L   * w0.x + m.x * w1.x + m.y * w2.x;
        a1 += m.x * w0.y + m.y * w1.y + m.z * w2.y;
        a2 += m.y * w0.z + m.z * w1.z + m.w * w2.z;
        a3 += m.z * w0.w + m.w * w1.w + R   * w2.w;
    }

    f32x4 o = {a0, a1, a2, a3};
    __builtin_nontemporal_store(o, (f32x4*)oc);
}

extern "C" void kernel_launch(void* const* d_in, const int* in_sizes, int n_in,
                              void* d_out, int out_size, void* d_ws, size_t ws_size,
                              hipStream_t stream) {
    const float* x = (const float*)d_in[0];
    const float* w = (const float*)d_in[1];
    float* out = (float*)d_out;

    const int total_threads = SKA_B * SKA_CW * 8 * SKA_H * SKA_Q;  // 1,605,632
    const int block = 256;
    const int grid = total_threads / block;                        // 6272

    ska_kernel<<<grid, block, 0, stream>>>(x, w, out);
}